// Round 8
// baseline (198.057 us; speedup 1.0000x reference)
//
#include <hip/hip_runtime.h>

// ---------------------------------------------------------------------------
// QuantizedLinear: y = x @ ((q - zp)*s)^T + bias    — INT8 MFMA path.
// Per-row x quant: s_x[m] = max|x[m,:]|/127, xq = rint(x/s_x)  (s8)
// Weight: qs8 = q - 128 (exact).  Then, EXACTLY (given quantized x):
//   y[m,o] = s_x[m]*s[o]*( G8[m,o] + (128-zp[o])*rq[m] ) + bias[o]
// Round 8: BK=64 (NT=64), LDS 64 KiB -> 2 blocks/CU (R7 was 128 KiB,
// 1 block/CU, measured time = SUM of MFMA+LDS pipes; co-resident blocks
// provide the cross-block overlap, m114). Fragment-contiguous LDS layout:
// staging lane l fetches (row w*16+(l&15), kslot l>>4) so ds_read is
// linear (base + m*1024 + lane*16), conflict-free, no XOR swizzle.
// Ledger (1-GLDS units): prologue vmcnt(2); p2 vmcnt(2); tile-end
// vmcnt(2) steady / vmcnt(0) last two tiles; lgkm 2/4/0.
// ---------------------------------------------------------------------------

typedef unsigned char u8;
typedef signed char s8;
typedef __attribute__((ext_vector_type(4))) int i32x4;
typedef __attribute__((ext_vector_type(4))) float f32x4;

#define M_TOK 8192
#define KDIM 4096
#define NDIM 4096
#define NT (KDIM / 64)  // 64 K-tiles of 64 i8

// --- helpers ---------------------------------------------------------------

__device__ __forceinline__ int pack4(int a, int b, int c, int d) {
  return (a & 255) | ((b & 255) << 8) | ((c & 255) << 16) |
         (int)(((unsigned)(d & 255)) << 24);
}

#define GLDS(gptr, lptr)                                                      \
  __builtin_amdgcn_global_load_lds(                                          \
      (const __attribute__((address_space(1))) void*)(gptr),                 \
      (__attribute__((address_space(3))) void*)(lptr), 16, 0, 0)

// --- kernel 1: x f32 -> s8 per-row quant, fused row max + row sum ----------

__global__ __launch_bounds__(256) void convert_x_kernel(
    const float* __restrict__ x, s8* __restrict__ xq,
    float* __restrict__ sx, float* __restrict__ rq) {
  const int row = blockIdx.x;
  const int tid = threadIdx.x;
  const float* xr = x + (size_t)row * KDIM + tid * 16;
  float4 v[4];
#pragma unroll
  for (int i = 0; i < 4; ++i) v[i] = ((const float4*)xr)[i];

  float mx = 0.f;
#pragma unroll
  for (int i = 0; i < 4; ++i) {
    mx = fmaxf(mx, fabsf(v[i].x)); mx = fmaxf(mx, fabsf(v[i].y));
    mx = fmaxf(mx, fabsf(v[i].z)); mx = fmaxf(mx, fabsf(v[i].w));
  }
#pragma unroll
  for (int off = 32; off > 0; off >>= 1)
    mx = fmaxf(mx, __shfl_down(mx, off, 64));
  __shared__ float redf[4];
  __shared__ float bmax;
  if ((tid & 63) == 0) redf[tid >> 6] = mx;
  __syncthreads();
  if (tid == 0)
    bmax = fmaxf(fmaxf(redf[0], redf[1]), fmaxf(redf[2], redf[3]));
  __syncthreads();
  const float maxv = bmax;
  const float inv = 127.0f / fmaxf(maxv, 1e-30f);

  int q[16];
  int ssum = 0;
#pragma unroll
  for (int i = 0; i < 4; ++i) {
    q[i * 4 + 0] = (int)rintf(v[i].x * inv);
    q[i * 4 + 1] = (int)rintf(v[i].y * inv);
    q[i * 4 + 2] = (int)rintf(v[i].z * inv);
    q[i * 4 + 3] = (int)rintf(v[i].w * inv);
  }
#pragma unroll
  for (int i = 0; i < 16; ++i) ssum += q[i];

  int4 o;
  o.x = pack4(q[0], q[1], q[2], q[3]);
  o.y = pack4(q[4], q[5], q[6], q[7]);
  o.z = pack4(q[8], q[9], q[10], q[11]);
  o.w = pack4(q[12], q[13], q[14], q[15]);
  *(int4*)(xq + (size_t)row * KDIM + tid * 16) = o;

#pragma unroll
  for (int off = 32; off > 0; off >>= 1) ssum += __shfl_down(ssum, off, 64);
  __shared__ int redi[4];
  if ((tid & 63) == 0) redi[tid >> 6] = ssum;
  __syncthreads();
  if (tid == 0) {
    sx[row] = maxv * (1.0f / 127.0f);
    rq[row] = (float)(redi[0] + redi[1] + redi[2] + redi[3]);  // < 2^24 exact
  }
}

// --- kernel 2: w int32 -> s8 (q - 128, exact) --------------------------------

__global__ __launch_bounds__(256) void convert_w_kernel(
    const int* __restrict__ wq, s8* __restrict__ wb) {
  const size_t idx = (size_t)blockIdx.x * 256 + threadIdx.x;  // 16 elems each
  const int4* src = (const int4*)wq + idx * 4;
  const int4 a = src[0], b = src[1], c = src[2], d = src[3];
  int4 o;
  o.x = pack4(a.x - 128, a.y - 128, a.z - 128, a.w - 128);
  o.y = pack4(b.x - 128, b.y - 128, b.z - 128, b.w - 128);
  o.z = pack4(c.x - 128, c.y - 128, c.z - 128, c.w - 128);
  o.w = pack4(d.x - 128, d.y - 128, d.z - 128, d.w - 128);
  ((int4*)wb)[idx] = o;
}

// --- kernel 3: 256x256 pipelined i8 GEMM, BK=64, fused dequant epilogue -----
// LDS: Al[2][2][8][1024] + Bl same = 64 KiB.  GLDS unit = one wave's 1 KiB
// block = 16 rows x 64 B, fragment-order (lane l holds row l&15, kslot l>>4).
// Per tile t: p0 reads b0-3 + stage B(t+1)h0; p1 reads a4-7 + stage B(t+1)h1;
// p2 vmcnt(2) [A(t+1) landed]; p3 reads NEXT a0-3 + stage A(t+2)h0+h1.
// One 16x16x64 MFMA per (m,n) per tile: 32 MFMAs/wave/tile in 4 quadrants.

__global__ __launch_bounds__(512, 2) void qlin_gemm_kernel(
    const u8* __restrict__ A,         // [M][K] s8 bits
    const u8* __restrict__ B,         // [N][K] s8 bits
    const float* __restrict__ sx,     // [M]
    const float* __restrict__ rq,     // [M]
    const float* __restrict__ scale,  // [N]
    const float* __restrict__ zp,     // [N]
    const float* __restrict__ bias,   // [N]
    float* __restrict__ out) {        // [M][N]
  extern __shared__ u8 lds[];
  u8* Al = lds;           // [2 dbuf][2 half][8 blk][1024 B]
  u8* Bl = lds + 32768;

  const int tid = threadIdx.x;
  const int lane = tid & 63;
  const int wave = tid >> 6;
  const int wm = wave >> 2;  // 0..1
  const int wn = wave & 3;   // 0..3

  // T1: bijective XCD swizzle (512 wgs, 512%8==0)
  const int bid = blockIdx.x;
  const int swz = (bid & 7) * 64 + (bid >> 3);
  const int bm = swz >> 4;   // 0..31
  const int bn = swz & 15;   // 0..15
  const int row0 = bm * 256, col0 = bn * 256;

  const int fr = lane & 15;  // fragment row
  const int fk = lane >> 4;  // k-slot
  // staging source: lane l -> (row wave*16+fr, k fk*16); 16 rows x 64 B
  // segments per GLDS. LDS dest wave-uniform; HW writes lane l at +l*16,
  // which IS the fragment slot by construction.
  const u8* Ags = A + (size_t)(row0 + wave * 16 + fr) * KDIM + fk * 16;
  const u8* Bgs = B + (size_t)(col0 + wave * 16 + fr) * KDIM + fk * 16;
  u8* AldW = Al + wave * 1024;
  u8* BldW = Bl + wave * 1024;

#define STAGE_A(d, tau, h)                                                    \
  GLDS(Ags + (size_t)(h) * 128 * KDIM + (tau) * 64,                          \
       AldW + (d) * 16384 + (h) * 8192)
#define STAGE_B(d, tau, h)                                                    \
  GLDS(Bgs + (size_t)(h) * 128 * KDIM + (tau) * 64,                          \
       BldW + (d) * 16384 + (h) * 8192)

  // fragment reads: A row (wm*128 + m*16 + fr) -> half wm, block m;
  // B row (wn*64 + n*16 + fr) -> half wn>>1, block (wn&1)*4+n. Linear slot.
  const u8* ArL = Al + wm * 8192 + lane * 16;
  const u8* BrL = Bl + (wn >> 1) * 8192 + (wn & 1) * 4096 + lane * 16;

#define LDA(d, m) (*(const i32x4*)(ArL + (d) * 16384 + (m) * 1024))
#define LDB(d, n) (*(const i32x4*)(BrL + (d) * 16384 + (n) * 1024))
#define MFMA(d, va, vb) \
  d = __builtin_amdgcn_mfma_i32_16x16x64_i8(va, vb, d, 0, 0, 0)

  i32x4 acc[8][4] = {};
  i32x4 a[8], b[4];

  // prologue: A(0), B(0), A(1) = 6 GLDS; vmcnt(2) -> tile0 landed
  STAGE_A(0, 0, 0); STAGE_A(0, 0, 1);
  STAGE_B(0, 0, 0); STAGE_B(0, 0, 1);
  STAGE_A(1, 1, 0); STAGE_A(1, 1, 1);
  asm volatile("s_waitcnt vmcnt(2)" ::: "memory");
  __builtin_amdgcn_s_barrier();
#pragma unroll
  for (int m = 0; m < 4; ++m) a[m] = LDA(0, m);

  for (int t = 0; t < NT; ++t) {
    const int d = t & 1;

    // ---- p0: read b0-1 | fence | b2-3 | stage B(t+1)h0 | lgkm(2) | q0 ----
    b[0] = LDB(d, 0); b[1] = LDB(d, 1);
    asm volatile("" ::: "memory");  // pin issue order for counted lgkm
    b[2] = LDB(d, 2); b[3] = LDB(d, 3);
    if (t + 1 < NT) STAGE_B(d ^ 1, t + 1, 0);
    __builtin_amdgcn_s_barrier();
    asm volatile("s_waitcnt lgkmcnt(2)" ::: "memory");  // a0-3, b0-1 ready
    __builtin_amdgcn_s_setprio(1);
#pragma unroll
    for (int m = 0; m < 4; ++m)
#pragma unroll
      for (int n = 0; n < 2; ++n) MFMA(acc[m][n], a[m], b[n]);
    __builtin_amdgcn_s_setprio(0);
    __builtin_amdgcn_s_barrier();

    // ---- p1: read a4-7 | stage B(t+1)h1 | lgkm(4) | q1 ----
#pragma unroll
    for (int m = 4; m < 8; ++m) a[m] = LDA(d, m);
    if (t + 1 < NT) STAGE_B(d ^ 1, t + 1, 1);
    __builtin_amdgcn_s_barrier();
    asm volatile("s_waitcnt lgkmcnt(4)" ::: "memory");  // b2-3 ready
    __builtin_amdgcn_s_setprio(1);
#pragma unroll
    for (int m = 0; m < 4; ++m)
#pragma unroll
      for (int n = 2; n < 4; ++n) MFMA(acc[m][n], a[m], b[n]);
    __builtin_amdgcn_s_setprio(0);
    __builtin_amdgcn_s_barrier();

    // ---- p2: vmcnt(2): A(t+1) landed | lgkm(0): a4-7 ready | q2 ----
    if (t + 1 < NT) {
      asm volatile("s_waitcnt vmcnt(2)" ::: "memory");
    }
    __builtin_amdgcn_s_barrier();
    asm volatile("s_waitcnt lgkmcnt(0)" ::: "memory");
    __builtin_amdgcn_s_setprio(1);
#pragma unroll
    for (int m = 4; m < 8; ++m)
#pragma unroll
      for (int n = 0; n < 2; ++n) MFMA(acc[m][n], a[m], b[n]);
    __builtin_amdgcn_s_setprio(0);
    __builtin_amdgcn_s_barrier();

    // ---- p3: read NEXT a0-3 | stage A(t+2)h0+h1 | q3 | tile-end vmcnt ----
    if (t + 1 < NT) {
#pragma unroll
      for (int m = 0; m < 4; ++m) a[m] = LDA(d ^ 1, m);
    }
    if (t + 2 < NT) { STAGE_A(d, t + 2, 0); STAGE_A(d, t + 2, 1); }
    __builtin_amdgcn_s_barrier();
    __builtin_amdgcn_s_setprio(1);
#pragma unroll
    for (int m = 4; m < 8; ++m)
#pragma unroll
      for (int n = 2; n < 4; ++n) MFMA(acc[m][n], a[m], b[n]);
    __builtin_amdgcn_s_setprio(0);
    if (t < NT - 2) {
      asm volatile("s_waitcnt vmcnt(2)" ::: "memory");  // B(t+1) landed
    } else {
      asm volatile("s_waitcnt vmcnt(0)" ::: "memory");  // tail drain
    }
    __builtin_amdgcn_s_barrier();
  }

  // --- epilogue: i32->f32, per-wave LDS transpose (16-row chunks),
  //     coalesced f32x4 stores.  scratch 8 x 4352 B = 34.8 KiB (reuses lds).
  // y = sx[row]*( s[col]*G + s[col]*(128-zp[col])*rq[row] ) + bias[col]
  {
    const int wrow0 = row0 + wm * 128;
    const int wcol0 = col0 + wn * 64;
    float* eps = (float*)lds + wave * 1088;  // 16*68 f32, wave-private
    const f32x4 p4 = *(const f32x4*)(scale + wcol0 + 4 * fr);
    const f32x4 z4 = *(const f32x4*)(zp + wcol0 + 4 * fr);
    const f32x4 b4 = *(const f32x4*)(bias + wcol0 + 4 * fr);
    const f32x4 w04 = p4 * (128.0f - z4);
#pragma unroll
    for (int c = 0; c < 8; ++c) {
#pragma unroll
      for (int n = 0; n < 4; ++n)
#pragma unroll
        for (int q = 0; q < 4; ++q)
          eps[(fk * 4 + q) * 68 + n * 16 + fr] = (float)acc[c][n][q];
      asm volatile("s_waitcnt lgkmcnt(0)" ::: "memory");
#pragma unroll
      for (int j = 0; j < 4; ++j) {
        const int rl = j * 4 + fk;                // 0..15
        const int grow = wrow0 + c * 16 + rl;
        const f32x4 v = *(const f32x4*)(eps + rl * 68 + 4 * fr);
        const float sxr = sx[grow];
        const float rqr = rq[grow];
        const f32x4 o4 = sxr * (p4 * v + w04 * rqr) + b4;
        *(f32x4*)(out + (size_t)grow * NDIM + wcol0 + 4 * fr) = o4;
      }
      asm volatile("s_waitcnt lgkmcnt(0)" ::: "memory");  // WAR before reuse
    }
  }
#undef STAGE_A
#undef STAGE_B
#undef LDA
#undef LDB
#undef MFMA
}

// --- launch ------------------------------------------------------------------

extern "C" void kernel_launch(void* const* d_in, const int* in_sizes, int n_in,
                              void* d_out, int out_size, void* d_ws,
                              size_t ws_size, hipStream_t stream) {
  const float* x = (const float*)d_in[0];
  const int* wq = (const int*)d_in[1];
  const float* scale = (const float*)d_in[2];
  const float* zp = (const float*)d_in[3];
  const float* bias = (const float*)d_in[4];
  float* out = (float*)d_out;

  // workspace: xq 32 MiB | wq8 16 MiB | sx 32 KiB | rq 32 KiB
  char* ws = (char*)d_ws;
  s8* xq = (s8*)ws;
  s8* wq8 = (s8*)(ws + (size_t)M_TOK * KDIM);
  float* sx = (float*)(ws + (size_t)M_TOK * KDIM + (size_t)NDIM * KDIM);
  float* rq = (float*)(ws + (size_t)M_TOK * KDIM + (size_t)NDIM * KDIM +
                       (size_t)M_TOK * 4);

  (void)hipFuncSetAttribute((const void*)qlin_gemm_kernel,
                            hipFuncAttributeMaxDynamicSharedMemorySize,
                            65536);

  convert_x_kernel<<<M_TOK, 256, 0, stream>>>(x, xq, sx, rq);
  convert_w_kernel<<<(NDIM * (size_t)KDIM) / (256 * 16), 256, 0, stream>>>(
      wq, wq8);

  qlin_gemm_kernel<<<dim3((M_TOK / 256) * (NDIM / 256)), dim3(512), 65536,
                     stream>>>((const u8*)xq, (const u8*)wq8, sx, rq, scale,
                               zp, bias, out);
}

// Round 9
// 172.827 us; speedup vs baseline: 1.1460x; 1.1460x over previous
//
#include <hip/hip_runtime.h>

// ---------------------------------------------------------------------------
// QuantizedLinear: y = x @ ((q - zp)*s)^T + bias    — INT8 MFMA path.
// Per-row x quant: s_x[m] = max|x[m,:]|/127, xq = rint(x/s_x)  (s8)
// Weight: qs8 = q - 128 (exact).  EXACT given quantized x:
//   y[m,o] = s_x[m]*s[o]*( G8[m,o] + (128-zp[o])*rq[m] ) + bias[o]
// Round 9: BK=128 (R7 revert — R8's BK=64 regressed: reg-capped at
// 2 waves/SIMD, halving MFMA/phase). NEW: 4 barriers/tile (was 8) —
// post-MFMA barriers deleted so leading waves' next-phase ds_reads overlap
// trailing waves' MFMAs (R7 measured = exact sum of MFMA+LDS pipes,
// MfmaUtil 42.5% = zero overlap).  Hazard ledger (per-wave GLDS order:
// A(t+1)[t-1 p2], B(t+1)h0[p0], h1[p1], A(t+2)[p2] = 12 outstanding at p3):
//  p0: read b0-3 | stage B(t+1)h0 | B0 | lgkm(4)  | q0
//  p1: read a4-7 | stage B(t+1)h1 | B1 | lgkm(8)  | q1
//  p2: lgkm(0) [a-reads of buf d done] | B2 | stage A(t+2)->buf d | q2
//  p3: vmcnt(4) [A(t+1),B(t+1) landed; A(t+2) in flight; 0 for t>=NT-2]
//      | B3 | read next a0-3 (buf d^1) | q3
// Every region's reads are lgkm-waited before a collective barrier that
// precedes the GLDS overwrite; every GLDS is vmcnt-drained by its issuer
// before a collective barrier that precedes its readers.
// ---------------------------------------------------------------------------

typedef unsigned char u8;
typedef signed char s8;
typedef __attribute__((ext_vector_type(4))) int i32x4;
typedef __attribute__((ext_vector_type(4))) float f32x4;

#define M_TOK 8192
#define KDIM 4096
#define NDIM 4096
#define NT (KDIM / 128)  // 32 K-tiles of 128 i8

// --- helpers ---------------------------------------------------------------

__device__ __forceinline__ int pack4(int a, int b, int c, int d) {
  return (a & 255) | ((b & 255) << 8) | ((c & 255) << 16) |
         (int)(((unsigned)(d & 255)) << 24);
}

#define GLDS(gptr, lptr)                                                      \
  __builtin_amdgcn_global_load_lds(                                          \
      (const __attribute__((address_space(1))) void*)(gptr),                 \
      (__attribute__((address_space(3))) void*)(lptr), 16, 0, 0)

// --- kernel 1: x f32 -> s8 per-row quant, fused row max + row sum ----------

__global__ __launch_bounds__(256) void convert_x_kernel(
    const float* __restrict__ x, s8* __restrict__ xq,
    float* __restrict__ sx, float* __restrict__ rq) {
  const int row = blockIdx.x;
  const int tid = threadIdx.x;
  const float* xr = x + (size_t)row * KDIM + tid * 16;
  float4 v[4];
#pragma unroll
  for (int i = 0; i < 4; ++i) v[i] = ((const float4*)xr)[i];

  float mx = 0.f;
#pragma unroll
  for (int i = 0; i < 4; ++i) {
    mx = fmaxf(mx, fabsf(v[i].x)); mx = fmaxf(mx, fabsf(v[i].y));
    mx = fmaxf(mx, fabsf(v[i].z)); mx = fmaxf(mx, fabsf(v[i].w));
  }
#pragma unroll
  for (int off = 32; off > 0; off >>= 1)
    mx = fmaxf(mx, __shfl_down(mx, off, 64));
  __shared__ float redf[4];
  __shared__ float bmax;
  if ((tid & 63) == 0) redf[tid >> 6] = mx;
  __syncthreads();
  if (tid == 0)
    bmax = fmaxf(fmaxf(redf[0], redf[1]), fmaxf(redf[2], redf[3]));
  __syncthreads();
  const float maxv = bmax;
  const float inv = 127.0f / fmaxf(maxv, 1e-30f);

  int q[16];
  int ssum = 0;
#pragma unroll
  for (int i = 0; i < 4; ++i) {
    q[i * 4 + 0] = (int)rintf(v[i].x * inv);
    q[i * 4 + 1] = (int)rintf(v[i].y * inv);
    q[i * 4 + 2] = (int)rintf(v[i].z * inv);
    q[i * 4 + 3] = (int)rintf(v[i].w * inv);
  }
#pragma unroll
  for (int i = 0; i < 16; ++i) ssum += q[i];

  int4 o;
  o.x = pack4(q[0], q[1], q[2], q[3]);
  o.y = pack4(q[4], q[5], q[6], q[7]);
  o.z = pack4(q[8], q[9], q[10], q[11]);
  o.w = pack4(q[12], q[13], q[14], q[15]);
  *(int4*)(xq + (size_t)row * KDIM + tid * 16) = o;

#pragma unroll
  for (int off = 32; off > 0; off >>= 1) ssum += __shfl_down(ssum, off, 64);
  __shared__ int redi[4];
  if ((tid & 63) == 0) redi[tid >> 6] = ssum;
  __syncthreads();
  if (tid == 0) {
    sx[row] = maxv * (1.0f / 127.0f);
    rq[row] = (float)(redi[0] + redi[1] + redi[2] + redi[3]);  // < 2^24 exact
  }
}

// --- kernel 2: w int32 -> s8 (q - 128, exact) --------------------------------

__global__ __launch_bounds__(256) void convert_w_kernel(
    const int* __restrict__ wq, s8* __restrict__ wb) {
  const size_t idx = (size_t)blockIdx.x * 256 + threadIdx.x;  // 16 elems each
  const int4* src = (const int4*)wq + idx * 4;
  const int4 a = src[0], b = src[1], c = src[2], d = src[3];
  int4 o;
  o.x = pack4(a.x - 128, a.y - 128, a.z - 128, a.w - 128);
  o.y = pack4(b.x - 128, b.y - 128, b.z - 128, b.w - 128);
  o.z = pack4(c.x - 128, c.y - 128, c.z - 128, c.w - 128);
  o.w = pack4(d.x - 128, d.y - 128, d.z - 128, d.w - 128);
  ((int4*)wb)[idx] = o;
}

// --- kernel 3: 256x256 i8 GEMM, BK=128, 4 barriers/tile ---------------------

__global__ __launch_bounds__(512, 2) void qlin_gemm_kernel(
    const u8* __restrict__ A,         // [M][K] s8 bits
    const u8* __restrict__ B,         // [N][K] s8 bits
    const float* __restrict__ sx,     // [M]
    const float* __restrict__ rq,     // [M]
    const float* __restrict__ scale,  // [N]
    const float* __restrict__ zp,     // [N]
    const float* __restrict__ bias,   // [N]
    float* __restrict__ out) {        // [M][N]
  extern __shared__ u8 lds[];
  u8* Al = lds;           // [2][256][128]
  u8* Bl = lds + 65536;   // [2][256][128]

  const int tid = threadIdx.x;
  const int lane = tid & 63;
  const int wave = tid >> 6;
  const int wm = wave >> 2;  // 0..1
  const int wn = wave & 3;   // 0..3

  // T1: bijective XCD swizzle (512 wgs, 512%8==0)
  const int bid = blockIdx.x;
  const int swz = (bid & 7) * 64 + (bid >> 3);
  const int bm = swz >> 4;   // 0..31
  const int bn = swz & 15;   // 0..15
  const int row0 = bm * 256, col0 = bn * 256;

  // staging: thread t -> row t>>3, slot (t&7)^(row&7) pre-swizzled source.
  const int sr = tid >> 3;
  const int ss = (tid & 7) ^ (sr & 7);
  const u8* Ags = A + (size_t)(row0 + sr) * KDIM + ss * 16;
  const u8* Bgs = B + (size_t)(col0 + sr) * KDIM + ss * 16;
  u8* Ald = Al + wave * 1024;
  u8* Bld = Bl + wave * 1024;

#define STAGE_A(d, tau, h)                                                    \
  do {                                                                        \
    const u8* _g = Ags + (size_t)(h) * 128 * KDIM + (tau) * 128;             \
    u8* _l = Ald + (d) * 32768 + (h) * 16384;                                \
    GLDS(_g, _l);                                                            \
    GLDS(_g + (size_t)64 * KDIM, _l + 8192);                                 \
  } while (0)

#define STAGE_B(d, tau, h)                                                    \
  do {                                                                        \
    const u8* _g = Bgs + (size_t)(h) * 128 * KDIM + (tau) * 128;             \
    u8* _l = Bld + (d) * 32768 + (h) * 16384;                                \
    GLDS(_g, _l);                                                            \
    GLDS(_g + (size_t)64 * KDIM, _l + 8192);                                 \
  } while (0)

  // fragment reads (XOR-swizzled, verified R7)
  const int r = lane & 15;
  const int g = lane >> 4;
  const int swzx = (lane & 7) << 4;
  const int ce0 = (g * 16) ^ swzx;        // bytes, ks=0
  const int ce1 = (64 + g * 16) ^ swzx;   // bytes, ks=1
  const u8* Ar = Al + (wm * 128 + r) * 128;
  const u8* Br = Bl + (wn * 64 + r) * 128;

#define LDA(base, m, ks) \
  (*(const i32x4*)((base) + (m) * 2048 + ((ks) ? ce1 : ce0)))
#define LDB(base, n, ks) \
  (*(const i32x4*)((base) + (n) * 2048 + ((ks) ? ce1 : ce0)))
#define MFMA(d, va, vb) \
  d = __builtin_amdgcn_mfma_i32_16x16x64_i8(va, vb, d, 0, 0, 0)

  i32x4 acc[8][4] = {};
  i32x4 a[8][2], b[4][2];

  // prologue: A(0), B(0), A(1) = 12 GLDS; vmcnt(4) -> A(0),B(0) landed.
  STAGE_A(0, 0, 0); STAGE_A(0, 0, 1);
  STAGE_B(0, 0, 0); STAGE_B(0, 0, 1);
  STAGE_A(1, 1, 0); STAGE_A(1, 1, 1);
  asm volatile("s_waitcnt vmcnt(4)" ::: "memory");
  __builtin_amdgcn_s_barrier();
#pragma unroll
  for (int m = 0; m < 4; ++m) {
    a[m][0] = LDA(Ar, m, 0); a[m][1] = LDA(Ar, m, 1);
  }

  for (int t = 0; t < NT; ++t) {
    const int d = t & 1;
    const u8* Ard = Ar + d * 32768;
    const u8* Brd = Br + d * 32768;
    const u8* ArdN = Ar + (d ^ 1) * 32768;

    // ---- p0: read b0-1 | fence | b2-3 | stage B(t+1)h0 | B0 | lgkm(4) | q0
#pragma unroll
    for (int n = 0; n < 2; ++n) {
      b[n][0] = LDB(Brd, n, 0); b[n][1] = LDB(Brd, n, 1);
    }
    asm volatile("" ::: "memory");  // pin b0-1 before b2-3 (counted lgkm)
#pragma unroll
    for (int n = 2; n < 4; ++n) {
      b[n][0] = LDB(Brd, n, 0); b[n][1] = LDB(Brd, n, 1);
    }
    if (t + 1 < NT) STAGE_B(d ^ 1, t + 1, 0);
    __builtin_amdgcn_s_barrier();
    asm volatile("s_waitcnt lgkmcnt(4)" ::: "memory");  // a0-3 + b0-1 ready
    __builtin_amdgcn_s_setprio(1);
#pragma unroll
    for (int ks = 0; ks < 2; ++ks)
#pragma unroll
      for (int m = 0; m < 4; ++m)
#pragma unroll
        for (int n = 0; n < 2; ++n) MFMA(acc[m][n], a[m][ks], b[n][ks]);
    __builtin_amdgcn_s_setprio(0);
    // no barrier: leading waves may start p1 reads under trailing MFMAs

    // ---- p1: read a4-7 | stage B(t+1)h1 | B1 | lgkm(8) | q1 ----
#pragma unroll
    for (int m = 4; m < 8; ++m) {
      a[m][0] = LDA(Ard, m, 0); a[m][1] = LDA(Ard, m, 1);
    }
    if (t + 1 < NT) STAGE_B(d ^ 1, t + 1, 1);
    __builtin_amdgcn_s_barrier();
    asm volatile("s_waitcnt lgkmcnt(8)" ::: "memory");  // b2-3 ready
    __builtin_amdgcn_s_setprio(1);
#pragma unroll
    for (int ks = 0; ks < 2; ++ks)
#pragma unroll
      for (int m = 0; m < 4; ++m)
#pragma unroll
        for (int n = 2; n < 4; ++n) MFMA(acc[m][n], a[m][ks], b[n][ks]);
    __builtin_amdgcn_s_setprio(0);

    // ---- p2: lgkm(0) [all own buf-d A reads done] | B2 | stage A(t+2) | q2
    asm volatile("s_waitcnt lgkmcnt(0)" ::: "memory");
    __builtin_amdgcn_s_barrier();  // => ALL waves' reads of buf d A complete
    if (t + 2 < NT) { STAGE_A(d, t + 2, 0); STAGE_A(d, t + 2, 1); }
    __builtin_amdgcn_s_setprio(1);
#pragma unroll
    for (int ks = 0; ks < 2; ++ks)
#pragma unroll
      for (int m = 4; m < 8; ++m)
#pragma unroll
        for (int n = 0; n < 2; ++n) MFMA(acc[m][n], a[m][ks], b[n][ks]);
    __builtin_amdgcn_s_setprio(0);

    // ---- p3: vmcnt | B3 | read next a0-3 | q3 ----
    if (t < NT - 2) {
      asm volatile("s_waitcnt vmcnt(4)" ::: "memory");  // A(t+1),B(t+1) landed
    } else {
      asm volatile("s_waitcnt vmcnt(0)" ::: "memory");  // tail drain
    }
    __builtin_amdgcn_s_barrier();  // => landed chip-wide before any read
    if (t + 1 < NT) {
#pragma unroll
      for (int m = 0; m < 4; ++m) {
        a[m][0] = LDA(ArdN, m, 0); a[m][1] = LDA(ArdN, m, 1);
      }
    }
    __builtin_amdgcn_s_setprio(1);
#pragma unroll
    for (int ks = 0; ks < 2; ++ks)
#pragma unroll
      for (int m = 4; m < 8; ++m)
#pragma unroll
        for (int n = 2; n < 4; ++n) MFMA(acc[m][n], a[m][ks], b[n][ks]);
    __builtin_amdgcn_s_setprio(0);
  }

  // --- epilogue: i32->f32, per-wave LDS transpose, coalesced f32x4 stores ---
  // y = sx[row]*( s[col]*G + s[col]*(128-zp[col])*rq[row] ) + bias[col]
  {
    const int wrow0 = row0 + wm * 128;
    const int wcol0 = col0 + wn * 64;
    float* eps = (float*)lds + wave * 2176;  // 32x68 f32, wave-private
    const f32x4 p4 = *(const f32x4*)(scale + wcol0 + 4 * r);
    const f32x4 z4 = *(const f32x4*)(zp + wcol0 + 4 * r);
    const f32x4 b4 = *(const f32x4*)(bias + wcol0 + 4 * r);
    const f32x4 w04 = p4 * (128.0f - z4);
#pragma unroll
    for (int c = 0; c < 4; ++c) {
#pragma unroll
      for (int mm = 0; mm < 2; ++mm)
#pragma unroll
        for (int n = 0; n < 4; ++n)
#pragma unroll
          for (int q = 0; q < 4; ++q)
            eps[(mm * 16 + g * 4 + q) * 68 + n * 16 + r] =
                (float)acc[2 * c + mm][n][q];
      asm volatile("s_waitcnt lgkmcnt(0)" ::: "memory");
#pragma unroll
      for (int j = 0; j < 8; ++j) {
        const int rl = j * 4 + g;                 // 0..31
        const int grow = wrow0 + c * 32 + rl;
        const f32x4 v = *(const f32x4*)(eps + rl * 68 + 4 * r);
        const float sxr = sx[grow];
        const float rqr = rq[grow];
        const f32x4 o4 = sxr * (p4 * v + w04 * rqr) + b4;
        *(f32x4*)(out + (size_t)grow * NDIM + wcol0 + 4 * r) = o4;
      }
      asm volatile("s_waitcnt lgkmcnt(0)" ::: "memory");  // WAR before reuse
    }
  }
#undef STAGE_A
#undef STAGE_B
#undef LDA
#undef LDB
#undef MFMA
}

// --- launch ------------------------------------------------------------------

extern "C" void kernel_launch(void* const* d_in, const int* in_sizes, int n_in,
                              void* d_out, int out_size, void* d_ws,
                              size_t ws_size, hipStream_t stream) {
  const float* x = (const float*)d_in[0];
  const int* wq = (const int*)d_in[1];
  const float* scale = (const float*)d_in[2];
  const float* zp = (const float*)d_in[3];
  const float* bias = (const float*)d_in[4];
  float* out = (float*)d_out;

  // workspace: xq 32 MiB | wq8 16 MiB | sx 32 KiB | rq 32 KiB
  char* ws = (char*)d_ws;
  s8* xq = (s8*)ws;
  s8* wq8 = (s8*)(ws + (size_t)M_TOK * KDIM);
  float* sx = (float*)(ws + (size_t)M_TOK * KDIM + (size_t)NDIM * KDIM);
  float* rq = (float*)(ws + (size_t)M_TOK * KDIM + (size_t)NDIM * KDIM +
                       (size_t)M_TOK * 4);

  (void)hipFuncSetAttribute((const void*)qlin_gemm_kernel,
                            hipFuncAttributeMaxDynamicSharedMemorySize,
                            131072);

  convert_x_kernel<<<M_TOK, 256, 0, stream>>>(x, xq, sx, rq);
  convert_w_kernel<<<(NDIM * (size_t)KDIM) / (256 * 16), 256, 0, stream>>>(
      wq, wq8);

  qlin_gemm_kernel<<<dim3((M_TOK / 256) * (NDIM / 256)), dim3(512), 131072,
                     stream>>>((const u8*)xq, (const u8*)wq8, sx, rq, scale,
                               zp, bias, out);
}

// Round 10
// 169.850 us; speedup vs baseline: 1.1661x; 1.0175x over previous
//
#include <hip/hip_runtime.h>

// ---------------------------------------------------------------------------
// QuantizedLinear: y = x @ ((q - zp)*s)^T + bias    — INT8 MFMA path.
// Per-row x quant: s_x[m] = max|x[m,:]|/127, xq = rint(x/s_x)  (s8)
// Weight: qs8 = q - 128 (exact).  EXACT given quantized x:
//   y[m,o] = s_x[m]*s[o]*( G8[m,o] + (128-zp[o])*rq[m] ) + bias[o]
// Round 10: 2 barriers/tile (was 4). B0/B1 removed after hazard audit —
// the lgkm(4)/(8) waits are per-wave (barrier-independent), and all
// cross-wave hazards are carried by B2 (WAR: lgkm(0)+barrier before
// A(t+2) staging) and B3 (RAW: vmcnt(4)+barrier before reading staged
// tiles). Waves now skew phases within a tile -> wave X's ds_read/lgkm
// stalls overlap wave Y's MFMAs on the same SIMD (m114 two-pipe overlap;
// T5 setprio now has a role split to arbitrate).
// Per-wave GLDS order: A(t+1)[t-1 p2], B(t+1)h0[p0], h1[p1], A(t+2)[p2]
// = 12 outstanding at p3; vmcnt(4) drains A(t+1)+B(t+1). Tail vmcnt(0).
// ---------------------------------------------------------------------------

typedef unsigned char u8;
typedef signed char s8;
typedef __attribute__((ext_vector_type(4))) int i32x4;
typedef __attribute__((ext_vector_type(4))) float f32x4;

#define M_TOK 8192
#define KDIM 4096
#define NDIM 4096
#define NT (KDIM / 128)  // 32 K-tiles of 128 i8

// --- helpers ---------------------------------------------------------------

__device__ __forceinline__ int pack4(int a, int b, int c, int d) {
  return (a & 255) | ((b & 255) << 8) | ((c & 255) << 16) |
         (int)(((unsigned)(d & 255)) << 24);
}

#define GLDS(gptr, lptr)                                                      \
  __builtin_amdgcn_global_load_lds(                                          \
      (const __attribute__((address_space(1))) void*)(gptr),                 \
      (__attribute__((address_space(3))) void*)(lptr), 16, 0, 0)

// --- kernel 1: x f32 -> s8 per-row quant, fused row max + row sum ----------

__global__ __launch_bounds__(256) void convert_x_kernel(
    const float* __restrict__ x, s8* __restrict__ xq,
    float* __restrict__ sx, float* __restrict__ rq) {
  const int row = blockIdx.x;
  const int tid = threadIdx.x;
  const float* xr = x + (size_t)row * KDIM + tid * 16;
  float4 v[4];
#pragma unroll
  for (int i = 0; i < 4; ++i) v[i] = ((const float4*)xr)[i];

  float mx = 0.f;
#pragma unroll
  for (int i = 0; i < 4; ++i) {
    mx = fmaxf(mx, fabsf(v[i].x)); mx = fmaxf(mx, fabsf(v[i].y));
    mx = fmaxf(mx, fabsf(v[i].z)); mx = fmaxf(mx, fabsf(v[i].w));
  }
#pragma unroll
  for (int off = 32; off > 0; off >>= 1)
    mx = fmaxf(mx, __shfl_down(mx, off, 64));
  __shared__ float redf[4];
  __shared__ float bmax;
  if ((tid & 63) == 0) redf[tid >> 6] = mx;
  __syncthreads();
  if (tid == 0)
    bmax = fmaxf(fmaxf(redf[0], redf[1]), fmaxf(redf[2], redf[3]));
  __syncthreads();
  const float maxv = bmax;
  const float inv = 127.0f / fmaxf(maxv, 1e-30f);

  int q[16];
  int ssum = 0;
#pragma unroll
  for (int i = 0; i < 4; ++i) {
    q[i * 4 + 0] = (int)rintf(v[i].x * inv);
    q[i * 4 + 1] = (int)rintf(v[i].y * inv);
    q[i * 4 + 2] = (int)rintf(v[i].z * inv);
    q[i * 4 + 3] = (int)rintf(v[i].w * inv);
  }
#pragma unroll
  for (int i = 0; i < 16; ++i) ssum += q[i];

  int4 o;
  o.x = pack4(q[0], q[1], q[2], q[3]);
  o.y = pack4(q[4], q[5], q[6], q[7]);
  o.z = pack4(q[8], q[9], q[10], q[11]);
  o.w = pack4(q[12], q[13], q[14], q[15]);
  *(int4*)(xq + (size_t)row * KDIM + tid * 16) = o;

#pragma unroll
  for (int off = 32; off > 0; off >>= 1) ssum += __shfl_down(ssum, off, 64);
  __shared__ int redi[4];
  if ((tid & 63) == 0) redi[tid >> 6] = ssum;
  __syncthreads();
  if (tid == 0) {
    sx[row] = maxv * (1.0f / 127.0f);
    rq[row] = (float)(redi[0] + redi[1] + redi[2] + redi[3]);  // < 2^24 exact
  }
}

// --- kernel 2: w int32 -> s8 (q - 128, exact) --------------------------------

__global__ __launch_bounds__(256) void convert_w_kernel(
    const int* __restrict__ wq, s8* __restrict__ wb) {
  const size_t idx = (size_t)blockIdx.x * 256 + threadIdx.x;  // 16 elems each
  const int4* src = (const int4*)wq + idx * 4;
  const int4 a = src[0], b = src[1], c = src[2], d = src[3];
  int4 o;
  o.x = pack4(a.x - 128, a.y - 128, a.z - 128, a.w - 128);
  o.y = pack4(b.x - 128, b.y - 128, b.z - 128, b.w - 128);
  o.z = pack4(c.x - 128, c.y - 128, c.z - 128, c.w - 128);
  o.w = pack4(d.x - 128, d.y - 128, d.z - 128, d.w - 128);
  ((int4*)wb)[idx] = o;
}

// --- kernel 3: 256x256 i8 GEMM, BK=128, 2 barriers/tile ---------------------

__global__ __launch_bounds__(512, 2) void qlin_gemm_kernel(
    const u8* __restrict__ A,         // [M][K] s8 bits
    const u8* __restrict__ B,         // [N][K] s8 bits
    const float* __restrict__ sx,     // [M]
    const float* __restrict__ rq,     // [M]
    const float* __restrict__ scale,  // [N]
    const float* __restrict__ zp,     // [N]
    const float* __restrict__ bias,   // [N]
    float* __restrict__ out) {        // [M][N]
  extern __shared__ u8 lds[];
  u8* Al = lds;           // [2][256][128]
  u8* Bl = lds + 65536;   // [2][256][128]

  const int tid = threadIdx.x;
  const int lane = tid & 63;
  const int wave = tid >> 6;
  const int wm = wave >> 2;  // 0..1
  const int wn = wave & 3;   // 0..3

  // T1: bijective XCD swizzle (512 wgs, 512%8==0)
  const int bid = blockIdx.x;
  const int swz = (bid & 7) * 64 + (bid >> 3);
  const int bm = swz >> 4;   // 0..31
  const int bn = swz & 15;   // 0..15
  const int row0 = bm * 256, col0 = bn * 256;

  // staging: thread t -> row t>>3, slot (t&7)^(row&7) pre-swizzled source.
  const int sr = tid >> 3;
  const int ss = (tid & 7) ^ (sr & 7);
  const u8* Ags = A + (size_t)(row0 + sr) * KDIM + ss * 16;
  const u8* Bgs = B + (size_t)(col0 + sr) * KDIM + ss * 16;
  u8* Ald = Al + wave * 1024;
  u8* Bld = Bl + wave * 1024;

#define STAGE_A(d, tau, h)                                                    \
  do {                                                                        \
    const u8* _g = Ags + (size_t)(h) * 128 * KDIM + (tau) * 128;             \
    u8* _l = Ald + (d) * 32768 + (h) * 16384;                                \
    GLDS(_g, _l);                                                            \
    GLDS(_g + (size_t)64 * KDIM, _l + 8192);                                 \
  } while (0)

#define STAGE_B(d, tau, h)                                                    \
  do {                                                                        \
    const u8* _g = Bgs + (size_t)(h) * 128 * KDIM + (tau) * 128;             \
    u8* _l = Bld + (d) * 32768 + (h) * 16384;                                \
    GLDS(_g, _l);                                                            \
    GLDS(_g + (size_t)64 * KDIM, _l + 8192);                                 \
  } while (0)

  // fragment reads (XOR-swizzled, verified R7)
  const int r = lane & 15;
  const int g = lane >> 4;
  const int swzx = (lane & 7) << 4;
  const int ce0 = (g * 16) ^ swzx;        // bytes, ks=0
  const int ce1 = (64 + g * 16) ^ swzx;   // bytes, ks=1
  const u8* Ar = Al + (wm * 128 + r) * 128;
  const u8* Br = Bl + (wn * 64 + r) * 128;

#define LDA(base, m, ks) \
  (*(const i32x4*)((base) + (m) * 2048 + ((ks) ? ce1 : ce0)))
#define LDB(base, n, ks) \
  (*(const i32x4*)((base) + (n) * 2048 + ((ks) ? ce1 : ce0)))
#define MFMA(d, va, vb) \
  d = __builtin_amdgcn_mfma_i32_16x16x64_i8(va, vb, d, 0, 0, 0)

  i32x4 acc[8][4] = {};
  i32x4 a[8][2], b[4][2];

  // prologue: A(0), B(0), A(1) = 12 GLDS; vmcnt(4) -> A(0),B(0) landed.
  STAGE_A(0, 0, 0); STAGE_A(0, 0, 1);
  STAGE_B(0, 0, 0); STAGE_B(0, 0, 1);
  STAGE_A(1, 1, 0); STAGE_A(1, 1, 1);
  asm volatile("s_waitcnt vmcnt(4)" ::: "memory");
  __builtin_amdgcn_s_barrier();
#pragma unroll
  for (int m = 0; m < 4; ++m) {
    a[m][0] = LDA(Ar, m, 0); a[m][1] = LDA(Ar, m, 1);
  }

  for (int t = 0; t < NT; ++t) {
    const int d = t & 1;
    const u8* Ard = Ar + d * 32768;
    const u8* Brd = Br + d * 32768;
    const u8* ArdN = Ar + (d ^ 1) * 32768;

    // ---- p0: read b0-1 | fence | b2-3 | stage B(t+1)h0 | lgkm(4) | q0 ----
    // (no barrier: per-wave lgkm count; region hazards covered by B3(t-1))
#pragma unroll
    for (int n = 0; n < 2; ++n) {
      b[n][0] = LDB(Brd, n, 0); b[n][1] = LDB(Brd, n, 1);
    }
    asm volatile("" ::: "memory");  // pin b0-1 before b2-3 (counted lgkm)
#pragma unroll
    for (int n = 2; n < 4; ++n) {
      b[n][0] = LDB(Brd, n, 0); b[n][1] = LDB(Brd, n, 1);
    }
    if (t + 1 < NT) STAGE_B(d ^ 1, t + 1, 0);
    asm volatile("s_waitcnt lgkmcnt(4)" ::: "memory");  // a0-3 + b0-1 ready
    __builtin_amdgcn_s_setprio(1);
#pragma unroll
    for (int ks = 0; ks < 2; ++ks)
#pragma unroll
      for (int m = 0; m < 4; ++m)
#pragma unroll
        for (int n = 0; n < 2; ++n) MFMA(acc[m][n], a[m][ks], b[n][ks]);
    __builtin_amdgcn_s_setprio(0);

    // ---- p1: read a4-7 | stage B(t+1)h1 | lgkm(8) | q1 ----
#pragma unroll
    for (int m = 4; m < 8; ++m) {
      a[m][0] = LDA(Ard, m, 0); a[m][1] = LDA(Ard, m, 1);
    }
    if (t + 1 < NT) STAGE_B(d ^ 1, t + 1, 1);
    asm volatile("s_waitcnt lgkmcnt(8)" ::: "memory");  // b2-3 ready
    __builtin_amdgcn_s_setprio(1);
#pragma unroll
    for (int ks = 0; ks < 2; ++ks)
#pragma unroll
      for (int m = 0; m < 4; ++m)
#pragma unroll
        for (int n = 2; n < 4; ++n) MFMA(acc[m][n], a[m][ks], b[n][ks]);
    __builtin_amdgcn_s_setprio(0);

    // ---- p2: lgkm(0) | B2 [all waves' buf-d A reads done] | stage A(t+2)
    //      | q2 ----
    asm volatile("s_waitcnt lgkmcnt(0)" ::: "memory");
    __builtin_amdgcn_s_barrier();  // B2: WAR fence for Al buf d
    if (t + 2 < NT) { STAGE_A(d, t + 2, 0); STAGE_A(d, t + 2, 1); }
    __builtin_amdgcn_s_setprio(1);
#pragma unroll
    for (int ks = 0; ks < 2; ++ks)
#pragma unroll
      for (int m = 4; m < 8; ++m)
#pragma unroll
        for (int n = 0; n < 2; ++n) MFMA(acc[m][n], a[m][ks], b[n][ks]);
    __builtin_amdgcn_s_setprio(0);

    // ---- p3: vmcnt | B3 [staged tiles landed chip-wide] | read next a0-3
    //      | q3 ----
    if (t < NT - 2) {
      asm volatile("s_waitcnt vmcnt(4)" ::: "memory");  // A(t+1),B(t+1) landed
    } else {
      asm volatile("s_waitcnt vmcnt(0)" ::: "memory");  // tail drain
    }
    __builtin_amdgcn_s_barrier();  // B3: RAW fence for staged data
    if (t + 1 < NT) {
#pragma unroll
      for (int m = 0; m < 4; ++m) {
        a[m][0] = LDA(ArdN, m, 0); a[m][1] = LDA(ArdN, m, 1);
      }
    }
    __builtin_amdgcn_s_setprio(1);
#pragma unroll
    for (int ks = 0; ks < 2; ++ks)
#pragma unroll
      for (int m = 4; m < 8; ++m)
#pragma unroll
        for (int n = 2; n < 4; ++n) MFMA(acc[m][n], a[m][ks], b[n][ks]);
    __builtin_amdgcn_s_setprio(0);
  }

  // --- epilogue: i32->f32, per-wave LDS transpose, coalesced f32x4 stores ---
  // y = sx[row]*( s[col]*G + s[col]*(128-zp[col])*rq[row] ) + bias[col]
  {
    const int wrow0 = row0 + wm * 128;
    const int wcol0 = col0 + wn * 64;
    float* eps = (float*)lds + wave * 2176;  // 32x68 f32, wave-private
    const f32x4 p4 = *(const f32x4*)(scale + wcol0 + 4 * r);
    const f32x4 z4 = *(const f32x4*)(zp + wcol0 + 4 * r);
    const f32x4 b4 = *(const f32x4*)(bias + wcol0 + 4 * r);
    const f32x4 w04 = p4 * (128.0f - z4);
#pragma unroll
    for (int c = 0; c < 4; ++c) {
#pragma unroll
      for (int mm = 0; mm < 2; ++mm)
#pragma unroll
        for (int n = 0; n < 4; ++n)
#pragma unroll
          for (int q = 0; q < 4; ++q)
            eps[(mm * 16 + g * 4 + q) * 68 + n * 16 + r] =
                (float)acc[2 * c + mm][n][q];
      asm volatile("s_waitcnt lgkmcnt(0)" ::: "memory");
#pragma unroll
      for (int j = 0; j < 8; ++j) {
        const int rl = j * 4 + g;                 // 0..31
        const int grow = wrow0 + c * 32 + rl;
        const f32x4 v = *(const f32x4*)(eps + rl * 68 + 4 * r);
        const float sxr = sx[grow];
        const float rqr = rq[grow];
        const f32x4 o4 = sxr * (p4 * v + w04 * rqr) + b4;
        *(f32x4*)(out + (size_t)grow * NDIM + wcol0 + 4 * r) = o4;
      }
      asm volatile("s_waitcnt lgkmcnt(0)" ::: "memory");  // WAR before reuse
    }
  }
#undef STAGE_A
#undef STAGE_B
#undef LDA
#undef LDB
#undef MFMA
}

// --- launch ------------------------------------------------------------------

extern "C" void kernel_launch(void* const* d_in, const int* in_sizes, int n_in,
                              void* d_out, int out_size, void* d_ws,
                              size_t ws_size, hipStream_t stream) {
  const float* x = (const float*)d_in[0];
  const int* wq = (const int*)d_in[1];
  const float* scale = (const float*)d_in[2];
  const float* zp = (const float*)d_in[3];
  const float* bias = (const float*)d_in[4];
  float* out = (float*)d_out;

  // workspace: xq 32 MiB | wq8 16 MiB | sx 32 KiB | rq 32 KiB
  char* ws = (char*)d_ws;
  s8* xq = (s8*)ws;
  s8* wq8 = (s8*)(ws + (size_t)M_TOK * KDIM);
  float* sx = (float*)(ws + (size_t)M_TOK * KDIM + (size_t)NDIM * KDIM);
  float* rq = (float*)(ws + (size_t)M_TOK * KDIM + (size_t)NDIM * KDIM +
                       (size_t)M_TOK * 4);

  (void)hipFuncSetAttribute((const void*)qlin_gemm_kernel,
                            hipFuncAttributeMaxDynamicSharedMemorySize,
                            131072);

  convert_x_kernel<<<M_TOK, 256, 0, stream>>>(x, xq, sx, rq);
  convert_w_kernel<<<(NDIM * (size_t)KDIM) / (256 * 16), 256, 0, stream>>>(
      wq, wq8);

  qlin_gemm_kernel<<<dim3((M_TOK / 256) * (NDIM / 256)), dim3(512), 131072,
                     stream>>>((const u8*)xq, (const u8*)wq8, sx, rq, scale,
                               zp, bias, out);
}